// Round 20
// baseline (360.962 us; speedup 1.0000x reference)
//
#include <hip/hip_runtime.h>
#include <hip/hip_bf16.h>

#define BB 4
#define TT 1024
#define DD 1024
#define HH 16
#define DKK 64
#define FFF 4096

typedef unsigned short u16;
typedef unsigned int u32;
typedef __attribute__((ext_vector_type(8))) short s16x8;
typedef __attribute__((ext_vector_type(4))) float f32x4;

static __device__ __forceinline__ float bf2f(u16 s) {
  union { u32 u; float f; } v; v.u = ((u32)s) << 16; return v.f;
}
static __device__ __forceinline__ u16 f2bf(float f) {
  union { float f; u32 u; } v; v.f = f;
  u32 r = v.u + 0x7FFFu + ((v.u >> 16) & 1u);
  return (u16)(r >> 16);
}

#define GLDS(gp, lp) __builtin_amdgcn_global_load_lds( \
    (const __attribute__((address_space(1))) u32*)(gp), \
    (__attribute__((address_space(3))) u32*)(lp), 16, 0, 0)

// XCD-chunked bijective block swizzle (m204 formula), 8-row supertiles.
static __device__ __forceinline__ void swz_block(int& bx, int& by) {
  int gx = gridDim.x, gy = gridDim.y;
  int nwg = gx * gy;
  int orig = by * gx + bx;
  int q = nwg >> 3, r = nwg & 7;
  int xcd = orig & 7, sl = orig >> 3;
  int wgid = (xcd < r ? xcd * (q + 1) : r * (q + 1) + (xcd - r) * q) + sl;
  int g = gx << 3;
  int grp = wgid / g, rem = wgid % g;
  bx = rem >> 3;
  by = (grp << 3) + (rem & 7);
}

// attention swizzle: 512 blocks (8 tiles x 64 bh); XCD j owns bh [8j, 8j+8) x all tiles.
static __device__ __forceinline__ void swz_attn(int& tileIdx, int& bh) {
  int orig = blockIdx.y * 8 + blockIdx.x;
  int wgid = ((orig & 7) << 6) | (orig >> 3);
  tileIdx = wgid & 7;
  bh = wgid >> 3;
}

// ---------------- ONE launch for all prep (segmented; heavy low-parallelism segs FIRST):
// [0,128): COALESCED masked softmax Wq1/Wk1 -> Bq/Bk       (128 blocks: 2w x 16h x 4cg)
// [128,1152): reorder Wv1->Bv, Wq2/Wk2/Wv2 -> B2 slabs     (256 blocks each)
// [1152,1664): transpose Wo1->Bwo1, Wo2->Bwo2              (256 blocks each)
// [1664,5760): elementwise x4-ILP: x->dout+xbf | y->ybf | w_in->Wi | w_out->Wob
//              (1024 blocks each; thread does 4 independent float4s)
__global__ __launch_bounds__(256) void k_prep_all(
    const float* __restrict__ x, float* __restrict__ dout, u16* __restrict__ xb,
    const float* __restrict__ y, u16* __restrict__ yb,
    const float* __restrict__ wi, u16* __restrict__ Wi,
    const float* __restrict__ wo, u16* __restrict__ Wob,
    const float* __restrict__ Wq1, const float* __restrict__ Wk1,
    u16* __restrict__ Bq, u16* __restrict__ Bk,
    const float* __restrict__ Wv1, u16* __restrict__ Bv,
    const float* __restrict__ Wq2, const float* __restrict__ Wk2, const float* __restrict__ Wv2,
    u16* __restrict__ B2,
    const float* __restrict__ Wo1, u16* __restrict__ Bwo1,
    const float* __restrict__ Wo2, u16* __restrict__ Bwo2) {
  __shared__ float red[256];
  __shared__ float t[64][65];
  int bid = blockIdx.x, tid = threadIdx.x;

  if (bid < 128) {         // coalesced masked softmax over d (no-max: |w|<=~0.1, exp-safe)
    int idx = bid;                  // 0..127
    int sel = idx >> 6;             // 0=Wq1, 1=Wk1
    int h   = (idx >> 2) & 15;
    int cg  = idx & 3;              // colgroup of 16
    const float* W = sel ? Wk1 : Wq1;
    u16* Bt = sel ? Bk : Bq;
    const float* wh = W + (size_t)h * DD * DKK;
    int c = tid & 15, rg = tid >> 4;
    int k = cg * 16 + c;            // col within 64 (mask threshold)
    // phase 1: coalesced strided-row read, 4 independent accumulators for ILP
    float s0 = 0.f, s1 = 0.f, s2 = 0.f, s3 = 0.f;
    for (int d = rg; d < DD; d += 64) {
      float v0 = wh[(size_t)d * DKK + k];
      float v1 = wh[(size_t)(d + 16) * DKK + k];
      float v2 = wh[(size_t)(d + 32) * DKK + k];
      float v3 = wh[(size_t)(d + 48) * DKK + k];
      if (d      >= k) s0 += __expf(v0);
      if (d + 16 >= k) s1 += __expf(v1);
      if (d + 32 >= k) s2 += __expf(v2);
      if (d + 48 >= k) s3 += __expf(v3);
    }
    red[tid] = (s0 + s1) + (s2 + s3); __syncthreads();
    #pragma unroll
    for (int s = 8; s > 0; s >>= 1) {
      if (rg < s) red[tid] += red[tid + s * 16];
      __syncthreads();
    }
    float rinv = 1.f / red[c];
    // phase 2: re-read (L2-hot) and write transposed bf16 row, coalesced 16B chunks
    u16* orow = Bt + ((size_t)(h * 64 + k)) * DD;
    for (int dd = rg * 64; dd < rg * 64 + 64; dd += 8) {
      u16 ob[8];
      #pragma unroll
      for (int e = 0; e < 8; ++e) {
        int d = dd + e;
        float v = (d >= k) ? __expf(wh[(size_t)d * DKK + k]) * rinv : 0.f;
        ob[e] = f2bf(v);
      }
      *(uint4*)(orow + dd) = *(const uint4*)ob;
    }
    return;
  }

  if (bid < 1152) {        // reorder (H,D,DK) -> B[n=h*64+k][d], 4 weights
    int idx = bid - 128;
    int zz = idx >> 8; idx &= 255;
    const float* W = (zz == 0) ? Wv1 : ((zz == 1) ? Wq2 : ((zz == 2) ? Wk2 : Wv2));
    u16* Bt = (zz == 0) ? Bv : (B2 + (size_t)(zz - 1) * 1024 * 1024);
    int d0 = (idx & 15) << 6, h = idx >> 4;
    const float* src = W + (size_t)h * DD * DKK + (size_t)d0 * DKK;
    #pragma unroll
    for (int i = 0; i < 16; ++i) {
      int e = i * 256 + tid; int r = e >> 6, c = e & 63;
      t[r][c] = src[(size_t)r * DKK + c];
    }
    __syncthreads();
    #pragma unroll
    for (int i = 0; i < 16; ++i) {
      int e = i * 256 + tid; int c = e >> 6, r = e & 63;
      Bt[((size_t)(h * 64 + c)) * DD + d0 + r] = f2bf(t[r][c]);
    }
    return;
  }

  if (bid < 1664) {        // transpose (K,N) -> B[n][k], Wo1 and Wo2
    int idx = bid - 1152;
    int sel = idx >> 8; idx &= 255;
    const float* W = sel ? Wo2 : Wo1;
    u16* Bt = sel ? Bwo2 : Bwo1;
    int k0 = (idx & 15) << 6, n0 = ((idx >> 4) & 15) << 6;
    #pragma unroll
    for (int i = 0; i < 16; ++i) {
      int e = i * 256 + tid; int r = e >> 6, c = e & 63;
      t[r][c] = W[(size_t)(k0 + r) * DD + n0 + c];
    }
    __syncthreads();
    #pragma unroll
    for (int i = 0; i < 16; ++i) {
      int e = i * 256 + tid; int c = e >> 6, r = e & 63;
      Bt[(size_t)(n0 + c) * DD + k0 + r] = f2bf(t[r][c]);
    }
    return;
  }

  {                        // elementwise conversions, 4 independent float4s per thread
    int idx = bid - 1664;
    int seg = idx >> 10;              // 1024 blocks per segment
    int inner = idx & 1023;
    const float* s = (seg == 0) ? x : ((seg == 1) ? y : ((seg == 2) ? wi : wo));
    u16* d = (seg == 0) ? xb : ((seg == 1) ? yb : ((seg == 2) ? Wi : Wob));
    int j0 = inner * 1024 + tid;      // float4 index; 4 chunks 256 apart
    float4 v0 = *(const float4*)(s + (size_t)(j0)        * 4);
    float4 v1 = *(const float4*)(s + (size_t)(j0 + 256)  * 4);
    float4 v2 = *(const float4*)(s + (size_t)(j0 + 512)  * 4);
    float4 v3 = *(const float4*)(s + (size_t)(j0 + 768)  * 4);
    if (seg == 0) {
      *(float4*)(dout + (size_t)(j0)       * 4) = v0;
      *(float4*)(dout + (size_t)(j0 + 256) * 4) = v1;
      *(float4*)(dout + (size_t)(j0 + 512) * 4) = v2;
      *(float4*)(dout + (size_t)(j0 + 768) * 4) = v3;
    }
    u16 o0[4] = { f2bf(v0.x), f2bf(v0.y), f2bf(v0.z), f2bf(v0.w) };
    u16 o1[4] = { f2bf(v1.x), f2bf(v1.y), f2bf(v1.z), f2bf(v1.w) };
    u16 o2[4] = { f2bf(v2.x), f2bf(v2.y), f2bf(v2.z), f2bf(v2.w) };
    u16 o3[4] = { f2bf(v3.x), f2bf(v3.y), f2bf(v3.z), f2bf(v3.w) };
    *(ushort4*)(d + (size_t)(j0)       * 4) = *(ushort4*)o0;
    *(ushort4*)(d + (size_t)(j0 + 256) * 4) = *(ushort4*)o1;
    *(ushort4*)(d + (size_t)(j0 + 512) * 4) = *(ushort4*)o2;
    *(ushort4*)(d + (size_t)(j0 + 768) * 4) = *(ushort4*)o3;
  }
}

// ---------------- MFMA NT GEMM: C = A(MxK) * B(NxK)^T (bf16 in, f32 acc) ----------------
// 128x128 tile, BK=32, 512 threads (8 waves 2x4, wave-tile 64x32), XCD swizzle,
// split-K via blockIdx.z, bf16 outputs via per-wave LDS slab.
// Pipeline: 3-buffer rotation, issue-ahead-2, counted s_waitcnt vmcnt(2) per K-step.
// T2 chunk-XOR swizzle on staging (both-sides). T5 setprio around the MFMA cluster.
__global__ __launch_bounds__(512) void k_mfma_nt(
    const u16* __restrict__ A, const u16* __restrict__ A2,
    const u16* __restrict__ B,
    u16* __restrict__ P0, u16* __restrict__ P1, u16* __restrict__ P2, u16* __restrict__ P3,
    u16* __restrict__ Cb, u16* __restrict__ Cb2, u16* __restrict__ Ct,
    const float* __restrict__ bias, int relu, int mode, int M, int N, int K) {
  __shared__ u16 SLDS[24576];   // A bufs [0,12288), B bufs [12288,24576); epilogue reuses [0,16384)
  int bx = blockIdx.x, by = blockIdx.y;
  swz_block(bx, by);
  int tid = threadIdx.x, wave = tid >> 6, lane = tid & 63;
  int row0 = by << 7, col0 = bx << 7;
  int wm = (wave >> 2) << 6;        // 0 / 64
  int wn = (wave & 3) << 5;         // 0 / 32 / 64 / 96

  const u16* Asrc = (mode == 1 && A2 && (col0 >> 10) > 0) ? A2 : A;

  int Ksl = K / gridDim.z;
  int kbase = blockIdx.z * Ksl;
  int nt = Ksl >> 5;                // K-steps of 32

  f32x4 acc[4][2];
  #pragma unroll
  for (int m = 0; m < 4; ++m)
    #pragma unroll
    for (int n = 0; n < 2; ++n) acc[m][n] = f32x4{0.f, 0.f, 0.f, 0.f};

  // staging: [128][32] bf16 = 8 KB per matrix; 512 threads x 16B = exactly one GLDS each.
  // source chunk pre-swizzled (rule #21): LDS (srow, tid&3) holds global chunk (tid&3)^((srow>>1)&3).
  int srow = tid >> 2;
  int scol = ((tid & 3) ^ ((srow >> 1) & 3)) << 3;
  const u16* Ag = Asrc + (size_t)(row0 + srow) * K + scol;
  const u16* Bg = B + (size_t)(col0 + srow) * K + scol;
  int wbase = wave << 9;            // u16 offset of this wave's 1KB chunk

  // read side: logical chunk (lane>>4) lives at physical chunk (lane>>4)^((fr>>1)&3).
  int fr = lane & 15;
  int kg = (((lane >> 4) ^ ((fr >> 1) & 3))) << 3;
  int ardo = (wm + fr) * 32 + kg;
  int brdo = 12288 + (wn + fr) * 32 + kg;

  auto STAGE = [&](int buf, int k0) {
    GLDS(Ag + k0, SLDS + buf * 4096 + wbase);
    GLDS(Bg + k0, SLDS + 12288 + buf * 4096 + wbase);
  };

  STAGE(0, kbase);
  if (nt > 1) STAGE(1, kbase + 32);
  int bufT = 0;
  for (int t = 0; t < nt; ++t) {
    // wait for buf[t]'s own loads; STAGE(t+1) (2 loads) may stay in flight
    if (t + 1 < nt) asm volatile("s_waitcnt vmcnt(2)" ::: "memory");
    else            asm volatile("s_waitcnt vmcnt(0)" ::: "memory");
    __builtin_amdgcn_s_barrier();     // all threads' buf[t] chunks landed
    asm volatile("" ::: "memory");
    if (t + 2 < nt) {
      int b2 = bufT + 2; if (b2 >= 3) b2 -= 3;
      STAGE(b2, kbase + (t + 2) * 32);  // overwrites buf[t-1]: safe, reads done pre-barrier
    }
    const u16* Ard = SLDS + bufT * 4096 + ardo;
    const u16* Brd = SLDS + bufT * 4096 + brdo;
    s16x8 aF[4], bF[2];
    #pragma unroll
    for (int m = 0; m < 4; ++m) aF[m] = *(const s16x8*)(Ard + m * 16 * 32);
    #pragma unroll
    for (int n = 0; n < 2; ++n) bF[n] = *(const s16x8*)(Brd + n * 16 * 32);
    __builtin_amdgcn_s_setprio(1);
    #pragma unroll
    for (int m = 0; m < 4; ++m)
      #pragma unroll
      for (int n = 0; n < 2; ++n)
        acc[m][n] = __builtin_amdgcn_mfma_f32_16x16x32_bf16(aF[m], bF[n], acc[m][n], 0, 0, 0);
    __builtin_amdgcn_s_setprio(0);
    ++bufT; if (bufT == 3) bufT = 0;
  }
  __syncthreads();                    // epilogue slab aliases staging bufs: wait all reads done

  int fq = (lane >> 4) << 2;

  // ---- all outputs bf16 via per-wave [16][40] LDS slab, 4 m-passes -> coalesced stores ----
  u16* dstRow = nullptr; u16* dstCol = nullptr;
  int rowPitch = 1024, colBase = col0 & 1023;
  if (mode == 0) {
    rowPitch = N; colBase = col0;
    if (gridDim.z > 1) {
      int z = blockIdx.z;
      dstRow = (z == 0) ? P0 : ((z == 1) ? P1 : ((z == 2) ? P2 : P3));
    } else dstRow = Cb;
  }
  else if (mode == 1) { int q = col0 >> 10; if (q == 0) dstRow = Cb; else if (q == 1) dstRow = Cb2; else dstCol = Ct; }
  else { int q = col0 >> 10; if (q == 0) dstRow = Cb; else dstCol = Ct; }

  u16* Ep = SLDS + wave * 2048;   // wave-private slab (16*40=640 u16 used)
  #pragma unroll
  for (int m = 0; m < 4; ++m) {
    #pragma unroll
    for (int n = 0; n < 2; ++n) {
      int col = col0 + wn + n * 16 + fr;
      float bs = bias ? bias[col] : 0.f;
      #pragma unroll
      for (int r = 0; r < 4; ++r) {
        float v = acc[m][n][r] + bs;
        if (relu) v = fmaxf(v, 0.f);
        Ep[(fq + r) * 40 + n * 16 + fr] = f2bf(v);
      }
    }
    if (dstRow) {
      int rw = lane >> 2, seg = lane & 3;                  // 16 rows x 4 segs of 8
      const u16* src = Ep + rw * 40 + seg * 8;
      u16* gd = dstRow + (size_t)(row0 + wm + m * 16 + rw) * rowPitch + colBase + wn + seg * 8;
      *(uint4*)gd = *(const uint4*)src;                    // 4 lanes x 16B = 64B line
    } else {
      int c = lane >> 1, half = lane & 1;                  // 32 cols x 2 halves of 8 rows
      u16 tmp[8];
      #pragma unroll
      for (int j = 0; j < 8; ++j) tmp[j] = Ep[(half * 8 + j) * 40 + c];
      u16* gd = dstCol + (size_t)(colBase + wn + c) * 4096 + row0 + wm + m * 16 + half * 8;
      *(uint4*)gd = *(const uint4*)tmp;                    // 2 lanes x 16B = 32B per col
    }
  }
}

// ---------------- stage one 64x64 bf16 tile (512 threads, 1 uint4 each) -> LDS [64][72] ----------------
static __device__ __forceinline__ void stage_tile512(const u16* __restrict__ g, int gp, u16* L, int tid) {
  int row = tid >> 3, col8 = (tid & 7) << 3;
  *(uint4*)(L + row * 72 + col8) = *(const uint4*)(g + (size_t)row * gp + col8);
}

// ---------------- attention pass 1 (MFMA, 8 waves, 2 s-tiles/block) ----------------
// csum[s] = sum_t exp(S[t][s]); no-max softmax (S small, exp-safe; shift-invariant).
__global__ __launch_bounds__(512) void k_attn_stats_mfma(const u16* __restrict__ Qb, const u16* __restrict__ Kb,
                                                         float* __restrict__ csum) {
  __shared__ u16 Ks[2 * 4608];
  __shared__ u16 Qs[4608];
  int tid = threadIdx.x, wave = tid >> 6, lane = tid & 63;
  int tileIdx, bh;
  swz_attn(tileIdx, bh);
  int b = bh >> 4, h = bh & 15;
  int s0 = tileIdx << 7;                  // 128 s-cols per block
  int tile = wave >> 2, sw = wave & 3;
  stage_tile512(Kb + ((size_t)(b * TT + s0)) * DD + h * 64, DD, Ks, tid);
  stage_tile512(Kb + ((size_t)(b * TT + s0 + 64)) * DD + h * 64, DD, Ks + 4608, tid);
  int row = tid >> 3, col8 = (tid & 7) << 3;
  const u16* Qg = Qb + ((size_t)(b * TT) + row) * DD + h * 64 + col8;
  uint4 qreg = *(const uint4*)Qg;          // tile t0=0
  __syncthreads();                          // Ks visible
  int fr = lane & 15, g = lane >> 4;
  const u16* Bbase = Ks + tile * 4608 + (sw * 16 + fr) * 72 + g * 8;   // B-frag: K rows (n = s)
  const u16* Abase = Qs + fr * 72 + g * 8;                             // A-frag: Q rows (m = t)
  s16x8 bF0 = *(const s16x8*)(Bbase);
  s16x8 bF1 = *(const s16x8*)(Bbase + 32);
  float sum = 0.f;
  for (int t0 = 0; t0 < TT; t0 += 64) {
    __syncthreads();                        // prior Qs reads done
    *(uint4*)(Qs + row * 72 + col8) = qreg;
    __syncthreads();                        // Qs visible
    if (t0 + 64 < TT) qreg = *(const uint4*)(Qg + (size_t)(t0 + 64) * DD);
    #pragma unroll
    for (int mt = 0; mt < 4; ++mt) {
      f32x4 acc = f32x4{0.f, 0.f, 0.f, 0.f};
      s16x8 a0 = *(const s16x8*)(Abase + mt * 16 * 72);
      s16x8 a1 = *(const s16x8*)(Abase + mt * 16 * 72 + 32);
      acc = __builtin_amdgcn_mfma_f32_16x16x32_bf16(a0, bF0, acc, 0, 0, 0);
      acc = __builtin_amdgcn_mfma_f32_16x16x32_bf16(a1, bF1, acc, 0, 0, 0);
      sum += __expf(acc[0] * 0.125f) + __expf(acc[1] * 0.125f)
           + __expf(acc[2] * 0.125f) + __expf(acc[3] * 0.125f);
    }
  }
  sum += __shfl_xor(sum, 16, 64);
  sum += __shfl_xor(sum, 32, 64);
  if (lane < 16) csum[(size_t)bh * TT + s0 + tile * 64 + sw * 16 + lane] = sum;
}

// ---------------- attention pass 2 (MFMA, 8 waves, 2 t-tiles/block) ----------------
__global__ __launch_bounds__(512) void k_attn_apply_mfma(const u16* __restrict__ Qb, const u16* __restrict__ Kb,
                                                         const u16* __restrict__ Vt,
                                                         const float* __restrict__ csum,
                                                         u16* __restrict__ Op) {
  __shared__ u16 Qs[2 * 4608];
  __shared__ u16 KV2[2 * 4608];    // Ks | VTs; reused by the write epilogue
  __shared__ u16 Pl[8 * 1024];     // per-wave [16 t][64 s] bf16, XOR-swizzled
  __shared__ float rcsL[64];
  u16* Ks = KV2;
  u16* VTs = KV2 + 4608;
  int tid = threadIdx.x, wave = tid >> 6, lane = tid & 63;
  int tileIdx, bh;
  swz_attn(tileIdx, bh);
  int b = bh >> 4, h = bh & 15;
  int t0 = tileIdx << 7;                  // 128 t-rows per block
  int tile = wave >> 2, tw = wave & 3;
  stage_tile512(Qb + ((size_t)(b * TT + t0)) * DD + h * 64, DD, Qs, tid);
  stage_tile512(Qb + ((size_t)(b * TT + t0 + 64)) * DD + h * 64, DD, Qs + 4608, tid);
  int row = tid >> 3, col8 = (tid & 7) << 3;
  const u16* Kg = Kb + ((size_t)(b * TT) + row) * DD + h * 64 + col8;
  const u16* Vg = Vt + ((size_t)(h * 64) + row) * 4096 + (size_t)b * TT + col8;
  const size_t cbase = (size_t)bh * TT;
  uint4 kreg = *(const uint4*)Kg;          // s0 = 0
  uint4 vreg = *(const uint4*)Vg;
  float rc0 = (tid < 64) ? csum[cbase + tid] : 0.f;
  __syncthreads();                          // Qs visible
  int fr = lane & 15, g = lane >> 4;
  const u16* QbF = Qs + tile * 4608 + (tw * 16 + fr) * 72 + g * 8;   // B-frag (n = t)
  const u16* KaF = Ks + fr * 72 + g * 8;                             // A-frag rows s
  char* Pw = (char*)(Pl + wave * 1024);
  uint swz = ((uint)(lane & 7)) << 4;
  s16x8 qF0 = *(const s16x8*)(QbF);
  s16x8 qF1 = *(const s16x8*)(QbF + 32);
  f32x4 acc_o[4];
  #pragma unroll
  for (int nt = 0; nt < 4; ++nt) acc_o[nt] = f32x4{0.f, 0.f, 0.f, 0.f};

  for (int s0 = 0; s0 < TT; s0 += 64) {
    __syncthreads();                        // prior Ks/VTs reads done
    *(uint4*)(Ks + row * 72 + col8) = kreg;
    *(uint4*)(VTs + row * 72 + col8) = vreg;
    if (tid < 64) rcsL[tid] = 1.f / rc0;
    __syncthreads();                        // visible
    if (s0 + 64 < TT) {                     // issue next-tile loads; hide under compute
      kreg = *(const uint4*)(Kg + (size_t)(s0 + 64) * DD);
      vreg = *(const uint4*)(Vg + s0 + 64);
      if (tid < 64) rc0 = csum[cbase + s0 + 64 + tid];
    }
    // S^T tiles + exp -> P (per-wave)
    #pragma unroll
    for (int mt = 0; mt < 4; ++mt) {
      f32x4 acc = f32x4{0.f, 0.f, 0.f, 0.f};
      s16x8 a0 = *(const s16x8*)(KaF + mt * 16 * 72);
      s16x8 a1 = *(const s16x8*)(KaF + mt * 16 * 72 + 32);
      acc = __builtin_amdgcn_mfma_f32_16x16x32_bf16(a0, qF0, acc, 0, 0, 0);
      acc = __builtin_amdgcn_mfma_f32_16x16x32_bf16(a1, qF1, acc, 0, 0, 0);
      f32x4 rc4 = *(const f32x4*)&rcsL[mt * 16 + g * 4];
      u16 pb[4];
      #pragma unroll
      for (int r = 0; r < 4; ++r)
        pb[r] = f2bf(__expf(acc[r] * 0.125f) * rc4[r]);
      uint woff = (uint)fr * 128 + (uint)(mt * 16 + g * 4) * 2;
      uint2 wv; wv.x = (u32)pb[0] | ((u32)pb[1] << 16); wv.y = (u32)pb[2] | ((u32)pb[3] << 16);
      *(uint2*)(Pw + (woff ^ swz)) = wv;
    }
    // PV: A = P (own wave's tile), B = V^T
    uint rbase = (uint)fr * 128;
    s16x8 pF0 = *(const s16x8*)(Pw + ((rbase + g * 16) ^ swz));
    s16x8 pF1 = *(const s16x8*)(Pw + ((rbase + 64 + g * 16) ^ swz));
    #pragma unroll
    for (int nt = 0; nt < 4; ++nt) {
      s16x8 v0 = *(const s16x8*)(VTs + (nt * 16 + fr) * 72 + g * 8);
      s16x8 v1 = *(const s16x8*)(VTs + (nt * 16 + fr) * 72 + 32 + g * 8);
      acc_o[nt] = __builtin_amdgcn_mfma_f32_16x16x32_bf16(pF0, v0, acc_o[nt], 0, 0, 0);
      acc_o[nt] = __builtin_amdgcn_mfma_f32_16x16x32_bf16(pF1, v1, acc_o[nt], 0, 0, 0);
    }
  }
  // write epilogue: per-wave LDS transpose (reuse KV2) -> coalesced 32B/lane stores
  __syncthreads();                         // all waves done reading Ks/VTs
  u16* Ep = KV2 + wave * 1088;             // per-wave [16][68]
  #pragma unroll
  for (int nt = 0; nt < 4; ++nt)
    #pragma unroll
    for (int r = 0; r < 4; ++r)
      Ep[(g * 4 + r) * 68 + nt * 16 + fr] = f2bf(acc_o[nt][r]);
  {
    int rw = lane >> 2, seg = lane & 3;
    const u16* src = Ep + rw * 68 + seg * 16;
    u16* gd = Op + ((size_t)(b * TT + t0 + tile * 64 + tw * 16 + rw)) * DD + h * 64 + seg * 16;
    #pragma unroll
    for (int i = 0; i < 4; ++i) *(uint2*)(gd + i * 4) = *(const uint2*)(src + i * 4);
  }
}

// ---------------- O = norm(sum of bf16 partials + bias + residual), ddof=1 ----------------
__global__ __launch_bounds__(256) void k_add_norm(const u16* __restrict__ A, const u16* __restrict__ A2,
                                                  const u16* __restrict__ A3, const u16* __restrict__ A4,
                                                  const float* __restrict__ bias,
                                                  const float* __restrict__ Bv,
                                                  float* __restrict__ O, u16* __restrict__ Ob) {
  int row = blockIdx.x, tid = threadIdx.x;
  size_t base = (size_t)row * DD;
  int c0 = tid * 4;
  __shared__ float red[256];
  float v[4];
  {
    ushort4 a = *(const ushort4*)(A + base + c0);
    float4 bv = *(const float4*)(Bv + base + c0);
    v[0] = bf2f(a.x) + bv.x; v[1] = bf2f(a.y) + bv.y;
    v[2] = bf2f(a.z) + bv.z; v[3] = bf2f(a.w) + bv.w;
  }
  if (A2) {
    ushort4 a = *(const ushort4*)(A2 + base + c0);
    v[0] += bf2f(a.x); v[1] += bf2f(a.y); v[2] += bf2f(a.z); v[3] += bf2f(a.w);
  }
  if (A3) {
    ushort4 a = *(const ushort4*)(A3 + base + c0);
    v[0] += bf2f(a.x); v[1] += bf2f(a.y); v[2] += bf2f(a.z); v[3] += bf2f(a.w);
  }
  if (A4) {
    ushort4 a = *(const ushort4*)(A4 + base + c0);
    v[0] += bf2f(a.x); v[1] += bf2f(a.y); v[2] += bf2f(a.z); v[3] += bf2f(a.w);
  }
  if (bias) {
    float4 bs = *(const float4*)(bias + c0);
    v[0] += bs.x; v[1] += bs.y; v[2] += bs.z; v[3] += bs.w;
  }
  float s = v[0] + v[1] + v[2] + v[3];
  red[tid] = s; __syncthreads();
  for (int t = 128; t > 0; t >>= 1) { if (tid < t) red[tid] += red[tid + t]; __syncthreads(); }
  float mean = red[0] * (1.f / 1024.f);
  __syncthreads();
  float vs = 0.f;
  #pragma unroll
  for (int i = 0; i < 4; ++i) { float d = v[i] - mean; vs += d * d; }
  red[tid] = vs; __syncthreads();
  for (int t = 128; t > 0; t >>= 1) { if (tid < t) red[tid] += red[tid + t]; __syncthreads(); }
  float inv = rsqrtf(red[0] * (1.f / 1023.f));
  float o[4];
  #pragma unroll
  for (int i = 0; i < 4; ++i) o[i] = (v[i] - mean) * inv;
  *(float4*)(O + base + c0) = *(float4*)o;
  if (Ob) {
    u16 ob[4] = { f2bf(o[0]), f2bf(o[1]), f2bf(o[2]), f2bf(o[3]) };
    *(ushort4*)(Ob + base + c0) = *(ushort4*)ob;
  }
}

extern "C" void kernel_launch(void* const* d_in, const int* in_sizes, int n_in,
                              void* d_out, int out_size, void* d_ws, size_t ws_size,
                              hipStream_t stream) {
  (void)in_sizes; (void)n_in; (void)out_size; (void)ws_size;
  const float* x    = (const float*)d_in[0];
  const float* y    = (const float*)d_in[1];
  const float* Wq1  = (const float*)d_in[2];
  const float* Wk1  = (const float*)d_in[3];
  const float* Wv1  = (const float*)d_in[4];
  const float* Wo1  = (const float*)d_in[5];
  const float* Wq2  = (const float*)d_in[6];
  const float* Wk2  = (const float*)d_in[7];
  const float* Wv2  = (const float*)d_in[8];
  const float* Wo2  = (const float*)d_in[9];
  const float* w_in  = (const float*)d_in[10];
  const float* b_in  = (const float*)d_in[11];
  const float* w_out = (const float*)d_in[12];
  const float* b_out = (const float*)d_in[13];

  float* ws = (float*)d_ws;
  size_t off = 0;
  auto allocw = [&](size_t nw) { float* p = ws + off; off += nw; return p; };
  const size_t MR = (size_t)BB * TT;           // 4096
  const size_t ND = MR * DD;                   // 4.19M elems

  u16* Bq   = (u16*)allocw(512 * 1024);        // Bq|Bk|Bv contiguous => fused B (3072 x 1024)
  u16* Bk   = (u16*)allocw(512 * 1024);
  u16* Bv   = (u16*)allocw(512 * 1024);
  u16* Bwo1 = (u16*)allocw(512 * 1024);
  u16* B2   = (u16*)allocw(3 * 512 * 1024);    // [Bq2|Bk2|Bv2] contiguous (3072 x 1024)
  u16* Bwo2 = (u16*)allocw(512 * 1024);
  u16* Wi   = (u16*)allocw(2 * 1024 * 1024);
  u16* Wob  = (u16*)allocw(2 * 1024 * 1024);
  u16* xbf  = (u16*)allocw(ND / 2);
  u16* ybf  = (u16*)allocw(ND / 2);
  u16* REG  = (u16*)allocw(ND * 2);
  float* ff2  = allocw(ND);                    // partial slabs p0|p1 (bf16)
  float* out1 = allocw(ND);                    // residual; later partial slabs p2|p3
  float* out2 = allocw(ND);
  float* csum = allocw((size_t)BB * HH * TT);

  u16* Qb = REG;
  u16* Kb = REG + ND;
  u16* Vt = REG + 2 * ND;   // V col-major (1024 x 4096), pitch 4096
  u16* Mb = REG + 3 * ND;   // mhaO; also out1_bf between layers
  u16* ff1b = REG;
  u16* out2bf = ybf;
  float* doutHi = (float*)d_out + ND;
  u16* p0 = (u16*)ff2;          // bf16 partial slabs
  u16* p1 = (u16*)ff2 + ND;
  u16* p2 = (u16*)out1;         // only after out1 is dead (FF2)
  u16* p3 = (u16*)out1 + ND;

  dim3 blk(256), blkG(512), blkA(512);
  dim3 gPrep(5760);
  dim3 gQKV(24, 32);         // N=3072
  dim3 gP2(8, 32, 2);        // N=1024, split-K=2
  dim3 gF1(32, 32);          // N=4096
  dim3 gFF2(8, 32, 4);       // N=1024, split-K=4 (K=4096)
  dim3 gAttn(8, 64);         // (tiles, bh) + swz_attn -> per-XCD bh grouping
  dim3 gNorm(MR);

  // ONE launch: all conversions + all weight transforms (heavy segments first)
  k_prep_all<<<gPrep, blk, 0, stream>>>(x, (float*)d_out, xbf, y, ybf, w_in, Wi, w_out, Wob,
                                        Wq1, Wk1, Bq, Bk, Wv1, Bv,
                                        Wq2, Wk2, Wv2, B2, Wo1, Bwo1, Wo2, Bwo2);

  // ---- Layer 1: masked self-attention on y ----
  k_mfma_nt<<<gQKV, blkG, 0, stream>>>(ybf, nullptr, Bq, nullptr, nullptr, nullptr, nullptr, Qb, Kb, Vt, nullptr, 0, 1, 4096, 3072, 1024);
  k_attn_stats_mfma<<<gAttn, blkA, 0, stream>>>(Qb, Kb, csum);
  k_attn_apply_mfma<<<gAttn, blkA, 0, stream>>>(Qb, Kb, Vt, csum, Mb);
  // out-proj split-K=2: bf16 partials p0,p1
  k_mfma_nt<<<gP2, blkG, 0, stream>>>(Mb, nullptr, Bwo1, p0, p1, nullptr, nullptr, nullptr, nullptr, nullptr, nullptr, 0, 0, 4096, 1024, 1024);
  k_add_norm<<<gNorm, blk, 0, stream>>>(p0, p1, nullptr, nullptr, nullptr, y, out1, Mb /* out1_bf */);

  // ---- Layer 2: cross-attention (Q from out1, K/V from x) ----
  // fused QKV2: Q-cols read A=Mb (out1_bf), K/V-cols read A2=xbf; B=[Bq2|Bk2|Bv2]
  k_mfma_nt<<<gQKV, blkG, 0, stream>>>(Mb, xbf, B2, nullptr, nullptr, nullptr, nullptr, Qb, Kb, Vt, nullptr, 0, 1, 4096, 3072, 1024);
  k_attn_stats_mfma<<<gAttn, blkA, 0, stream>>>(Qb, Kb, csum);
  k_attn_apply_mfma<<<gAttn, blkA, 0, stream>>>(Qb, Kb, Vt, csum, Mb);
  // out-proj split-K=2: bf16 partials p0,p1
  k_mfma_nt<<<gP2, blkG, 0, stream>>>(Mb, nullptr, Bwo2, p0, p1, nullptr, nullptr, nullptr, nullptr, nullptr, nullptr, 0, 0, 4096, 1024, 1024);
  k_add_norm<<<gNorm, blk, 0, stream>>>(p0, p1, nullptr, nullptr, nullptr, out1, out2, out2bf);

  // ---- FF ----  (out1 dead from here; p2/p3 alias it)
  k_mfma_nt<<<gF1, blkG, 0, stream>>>(out2bf, nullptr, Wi, nullptr, nullptr, nullptr, nullptr, ff1b, nullptr, nullptr, b_in, 1, 0, 4096, 4096, 1024);
  // FF2 split-K=4: bf16 partials p0..p3; bias ONCE in final norm
  k_mfma_nt<<<gFF2, blkG, 0, stream>>>(ff1b, nullptr, Wob, p0, p1, p2, p3, nullptr, nullptr, nullptr, nullptr, 0, 0, 4096, 1024, 4096);
  k_add_norm<<<gNorm, blk, 0, stream>>>(p0, p1, p2, p3, b_out, out2, doutHi, nullptr);
}

// Round 21
// 358.965 us; speedup vs baseline: 1.0056x; 1.0056x over previous
//
#include <hip/hip_runtime.h>
#include <hip/hip_bf16.h>

#define BB 4
#define TT 1024
#define DD 1024
#define HH 16
#define DKK 64
#define FFF 4096

typedef unsigned short u16;
typedef unsigned int u32;
typedef __attribute__((ext_vector_type(8))) short s16x8;
typedef __attribute__((ext_vector_type(4))) float f32x4;

static __device__ __forceinline__ float bf2f(u16 s) {
  union { u32 u; float f; } v; v.u = ((u32)s) << 16; return v.f;
}
static __device__ __forceinline__ u16 f2bf(float f) {
  union { float f; u32 u; } v; v.f = f;
  u32 r = v.u + 0x7FFFu + ((v.u >> 16) & 1u);
  return (u16)(r >> 16);
}

#define GLDS(gp, lp) __builtin_amdgcn_global_load_lds( \
    (const __attribute__((address_space(1))) u32*)(gp), \
    (__attribute__((address_space(3))) u32*)(lp), 16, 0, 0)

// XCD-chunked bijective block swizzle (m204 formula), 8-row supertiles.
static __device__ __forceinline__ void swz_block(int& bx, int& by) {
  int gx = gridDim.x, gy = gridDim.y;
  int nwg = gx * gy;
  int orig = by * gx + bx;
  int q = nwg >> 3, r = nwg & 7;
  int xcd = orig & 7, sl = orig >> 3;
  int wgid = (xcd < r ? xcd * (q + 1) : r * (q + 1) + (xcd - r) * q) + sl;
  int g = gx << 3;
  int grp = wgid / g, rem = wgid % g;
  bx = rem >> 3;
  by = (grp << 3) + (rem & 7);
}

// attention swizzle: 512 blocks (8 tiles x 64 bh); XCD j owns bh [8j, 8j+8) x all tiles.
static __device__ __forceinline__ void swz_attn(int& tileIdx, int& bh) {
  int orig = blockIdx.y * 8 + blockIdx.x;
  int wgid = ((orig & 7) << 6) | (orig >> 3);
  tileIdx = wgid & 7;
  bh = wgid >> 3;
}

// ---------------- ONE launch for all prep (segmented; heavy low-parallelism segs FIRST):
// [0,128): COALESCED masked softmax Wq1/Wk1 -> Bq/Bk       (128 blocks: 2w x 16h x 4cg)
// [128,1152): reorder Wv1->Bv, Wq2/Wk2/Wv2 -> B2 slabs     (256 blocks each, vec writes)
// [1152,1664): transpose Wo1->Bwo1, Wo2->Bwo2              (256 blocks each, vec writes)
// [1664,18048): x->dout+xbf | y->ybf | w_in->Wi | w_out->Wob (4096 blocks each, 1 float4/thread)
__global__ __launch_bounds__(256) void k_prep_all(
    const float* __restrict__ x, float* __restrict__ dout, u16* __restrict__ xb,
    const float* __restrict__ y, u16* __restrict__ yb,
    const float* __restrict__ wi, u16* __restrict__ Wi,
    const float* __restrict__ wo, u16* __restrict__ Wob,
    const float* __restrict__ Wq1, const float* __restrict__ Wk1,
    u16* __restrict__ Bq, u16* __restrict__ Bk,
    const float* __restrict__ Wv1, u16* __restrict__ Bv,
    const float* __restrict__ Wq2, const float* __restrict__ Wk2, const float* __restrict__ Wv2,
    u16* __restrict__ B2,
    const float* __restrict__ Wo1, u16* __restrict__ Bwo1,
    const float* __restrict__ Wo2, u16* __restrict__ Bwo2) {
  __shared__ float red[256];
  __shared__ float t[64][65];
  int bid = blockIdx.x, tid = threadIdx.x;

  if (bid < 128) {         // coalesced masked softmax over d (no-max: |w|<=~0.1, exp-safe)
    int idx = bid;                  // 0..127
    int sel = idx >> 6;             // 0=Wq1, 1=Wk1
    int h   = (idx >> 2) & 15;
    int cg  = idx & 3;              // colgroup of 16
    const float* W = sel ? Wk1 : Wq1;
    u16* Bt = sel ? Bk : Bq;
    const float* wh = W + (size_t)h * DD * DKK;
    int c = tid & 15, rg = tid >> 4;
    int k = cg * 16 + c;            // col within 64 (mask threshold)
    // phase 1: coalesced strided-row read, 4 independent accumulators for ILP
    float s0 = 0.f, s1 = 0.f, s2 = 0.f, s3 = 0.f;
    for (int d = rg; d < DD; d += 64) {
      float v0 = wh[(size_t)d * DKK + k];
      float v1 = wh[(size_t)(d + 16) * DKK + k];
      float v2 = wh[(size_t)(d + 32) * DKK + k];
      float v3 = wh[(size_t)(d + 48) * DKK + k];
      if (d      >= k) s0 += __expf(v0);
      if (d + 16 >= k) s1 += __expf(v1);
      if (d + 32 >= k) s2 += __expf(v2);
      if (d + 48 >= k) s3 += __expf(v3);
    }
    red[tid] = (s0 + s1) + (s2 + s3); __syncthreads();
    #pragma unroll
    for (int s = 8; s > 0; s >>= 1) {
      if (rg < s) red[tid] += red[tid + s * 16];
      __syncthreads();
    }
    float rinv = 1.f / red[c];
    // phase 2: re-read (L2-hot) and write transposed bf16 row, coalesced 16B chunks
    u16* orow = Bt + ((size_t)(h * 64 + k)) * DD;
    for (int dd = rg * 64; dd < rg * 64 + 64; dd += 8) {
      u16 ob[8];
      #pragma unroll
      for (int e = 0; e < 8; ++e) {
        int d = dd + e;
        float v = (d >= k) ? __expf(wh[(size_t)d * DKK + k]) * rinv : 0.f;
        ob[e] = f2bf(v);
      }
      *(uint4*)(orow + dd) = *(const uint4*)ob;
    }
    return;
  }

  if (bid < 1152) {        // reorder (H,D,DK) -> B[n=h*64+k][d], 4 weights (vec writes)
    int idx = bid - 128;
    int zz = idx >> 8; idx &= 255;
    const float* W = (zz == 0) ? Wv1 : ((zz == 1) ? Wq2 : ((zz == 2) ? Wk2 : Wv2));
    u16* Bt = (zz == 0) ? Bv : (B2 + (size_t)(zz - 1) * 1024 * 1024);
    int d0 = (idx & 15) << 6, h = idx >> 4;
    const float* src = W + (size_t)h * DD * DKK + (size_t)d0 * DKK;
    #pragma unroll
    for (int i = 0; i < 16; ++i) {
      int e = i * 256 + tid; int r = e >> 6, c = e & 63;
      t[r][c] = src[(size_t)r * DKK + c];
    }
    __syncthreads();
    // write: thread (c, grp) packs 8 consecutive-d bf16 -> one uint4 (coalesced)
    #pragma unroll
    for (int it = 0; it < 2; ++it) {
      int e = it * 256 + tid;
      int c = e >> 3, grp = e & 7;
      u16 ob[8];
      #pragma unroll
      for (int j = 0; j < 8; ++j) ob[j] = f2bf(t[grp * 8 + j][c]);
      *(uint4*)(Bt + ((size_t)(h * 64 + c)) * DD + d0 + grp * 8) = *(const uint4*)ob;
    }
    return;
  }

  if (bid < 1664) {        // transpose (K,N) -> B[n][k], Wo1 and Wo2 (vec writes)
    int idx = bid - 1152;
    int sel = idx >> 8; idx &= 255;
    const float* W = sel ? Wo2 : Wo1;
    u16* Bt = sel ? Bwo2 : Bwo1;
    int k0 = (idx & 15) << 6, n0 = ((idx >> 4) & 15) << 6;
    #pragma unroll
    for (int i = 0; i < 16; ++i) {
      int e = i * 256 + tid; int r = e >> 6, c = e & 63;
      t[r][c] = W[(size_t)(k0 + r) * DD + n0 + c];
    }
    __syncthreads();
    #pragma unroll
    for (int it = 0; it < 2; ++it) {
      int e = it * 256 + tid;
      int c = e >> 3, grp = e & 7;
      u16 ob[8];
      #pragma unroll
      for (int j = 0; j < 8; ++j) ob[j] = f2bf(t[grp * 8 + j][c]);
      *(uint4*)(Bt + (size_t)(n0 + c) * DD + k0 + grp * 8) = *(const uint4*)ob;
    }
    return;
  }

  {                        // elementwise conversions (R19 form: 1 float4/thread, max blocks)
    int idx = bid - 1664;
    int seg = idx >> 12;
    int i = ((idx & 4095) * 256 + tid) * 4;
    if (seg == 0) {
      float4 v = *(const float4*)(x + i);
      *(float4*)(dout + i) = v;
      u16 o[4] = { f2bf(v.x), f2bf(v.y), f2bf(v.z), f2bf(v.w) };
      *(ushort4*)(xb + i) = *(ushort4*)o;
    } else {
      const float* s = (seg == 1) ? y : ((seg == 2) ? wi : wo);
      u16* d = (seg == 1) ? yb : ((seg == 2) ? Wi : Wob);
      float4 v = *(const float4*)(s + i);
      u16 o[4] = { f2bf(v.x), f2bf(v.y), f2bf(v.z), f2bf(v.w) };
      *(ushort4*)(d + i) = *(ushort4*)o;
    }
  }
}

// ---------------- MFMA NT GEMM: C = A(MxK) * B(NxK)^T (bf16 in, f32 acc) ----------------
// 128x128 tile, BK=32, 512 threads (8 waves 2x4, wave-tile 64x32), XCD swizzle,
// split-K via blockIdx.z, bf16 outputs via per-wave LDS slab.
// Pipeline: 3-buffer rotation, issue-ahead-2, counted s_waitcnt vmcnt(2) per K-step.
// T2 chunk-XOR swizzle on staging (both-sides). T5 setprio around the MFMA cluster.
__global__ __launch_bounds__(512) void k_mfma_nt(
    const u16* __restrict__ A, const u16* __restrict__ A2,
    const u16* __restrict__ B,
    u16* __restrict__ P0, u16* __restrict__ P1, u16* __restrict__ P2, u16* __restrict__ P3,
    u16* __restrict__ Cb, u16* __restrict__ Cb2, u16* __restrict__ Ct,
    const float* __restrict__ bias, int relu, int mode, int M, int N, int K) {
  __shared__ u16 SLDS[24576];   // A bufs [0,12288), B bufs [12288,24576); epilogue reuses [0,16384)
  int bx = blockIdx.x, by = blockIdx.y;
  swz_block(bx, by);
  int tid = threadIdx.x, wave = tid >> 6, lane = tid & 63;
  int row0 = by << 7, col0 = bx << 7;
  int wm = (wave >> 2) << 6;        // 0 / 64
  int wn = (wave & 3) << 5;         // 0 / 32 / 64 / 96

  const u16* Asrc = (mode == 1 && A2 && (col0 >> 10) > 0) ? A2 : A;

  int Ksl = K / gridDim.z;
  int kbase = blockIdx.z * Ksl;
  int nt = Ksl >> 5;                // K-steps of 32

  f32x4 acc[4][2];
  #pragma unroll
  for (int m = 0; m < 4; ++m)
    #pragma unroll
    for (int n = 0; n < 2; ++n) acc[m][n] = f32x4{0.f, 0.f, 0.f, 0.f};

  // staging: [128][32] bf16 = 8 KB per matrix; 512 threads x 16B = exactly one GLDS each.
  // source chunk pre-swizzled (rule #21): LDS (srow, tid&3) holds global chunk (tid&3)^((srow>>1)&3).
  int srow = tid >> 2;
  int scol = ((tid & 3) ^ ((srow >> 1) & 3)) << 3;
  const u16* Ag = Asrc + (size_t)(row0 + srow) * K + scol;
  const u16* Bg = B + (size_t)(col0 + srow) * K + scol;
  int wbase = wave << 9;            // u16 offset of this wave's 1KB chunk

  // read side: logical chunk (lane>>4) lives at physical chunk (lane>>4)^((fr>>1)&3).
  int fr = lane & 15;
  int kg = (((lane >> 4) ^ ((fr >> 1) & 3))) << 3;
  int ardo = (wm + fr) * 32 + kg;
  int brdo = 12288 + (wn + fr) * 32 + kg;

  auto STAGE = [&](int buf, int k0) {
    GLDS(Ag + k0, SLDS + buf * 4096 + wbase);
    GLDS(Bg + k0, SLDS + 12288 + buf * 4096 + wbase);
  };

  STAGE(0, kbase);
  if (nt > 1) STAGE(1, kbase + 32);
  int bufT = 0;
  for (int t = 0; t < nt; ++t) {
    // wait for buf[t]'s own loads; STAGE(t+1) (2 loads) may stay in flight
    if (t + 1 < nt) asm volatile("s_waitcnt vmcnt(2)" ::: "memory");
    else            asm volatile("s_waitcnt vmcnt(0)" ::: "memory");
    __builtin_amdgcn_s_barrier();     // all threads' buf[t] chunks landed
    asm volatile("" ::: "memory");
    if (t + 2 < nt) {
      int b2 = bufT + 2; if (b2 >= 3) b2 -= 3;
      STAGE(b2, kbase + (t + 2) * 32);  // overwrites buf[t-1]: safe, reads done pre-barrier
    }
    const u16* Ard = SLDS + bufT * 4096 + ardo;
    const u16* Brd = SLDS + bufT * 4096 + brdo;
    s16x8 aF[4], bF[2];
    #pragma unroll
    for (int m = 0; m < 4; ++m) aF[m] = *(const s16x8*)(Ard + m * 16 * 32);
    #pragma unroll
    for (int n = 0; n < 2; ++n) bF[n] = *(const s16x8*)(Brd + n * 16 * 32);
    __builtin_amdgcn_s_setprio(1);
    #pragma unroll
    for (int m = 0; m < 4; ++m)
      #pragma unroll
      for (int n = 0; n < 2; ++n)
        acc[m][n] = __builtin_amdgcn_mfma_f32_16x16x32_bf16(aF[m], bF[n], acc[m][n], 0, 0, 0);
    __builtin_amdgcn_s_setprio(0);
    ++bufT; if (bufT == 3) bufT = 0;
  }
  __syncthreads();                    // epilogue slab aliases staging bufs: wait all reads done

  int fq = (lane >> 4) << 2;

  // ---- all outputs bf16 via per-wave [16][40] LDS slab, 4 m-passes -> coalesced stores ----
  u16* dstRow = nullptr; u16* dstCol = nullptr;
  int rowPitch = 1024, colBase = col0 & 1023;
  if (mode == 0) {
    rowPitch = N; colBase = col0;
    if (gridDim.z > 1) {
      int z = blockIdx.z;
      dstRow = (z == 0) ? P0 : ((z == 1) ? P1 : ((z == 2) ? P2 : P3));
    } else dstRow = Cb;
  }
  else if (mode == 1) { int q = col0 >> 10; if (q == 0) dstRow = Cb; else if (q == 1) dstRow = Cb2; else dstCol = Ct; }
  else { int q = col0 >> 10; if (q == 0) dstRow = Cb; else dstCol = Ct; }

  u16* Ep = SLDS + wave * 2048;   // wave-private slab (16*40=640 u16 used)
  #pragma unroll
  for (int m = 0; m < 4; ++m) {
    #pragma unroll
    for (int n = 0; n < 2; ++n) {
      int col = col0 + wn + n * 16 + fr;
      float bs = bias ? bias[col] : 0.f;
      #pragma unroll
      for (int r = 0; r < 4; ++r) {
        float v = acc[m][n][r] + bs;
        if (relu) v = fmaxf(v, 0.f);
        Ep[(fq + r) * 40 + n * 16 + fr] = f2bf(v);
      }
    }
    if (dstRow) {
      int rw = lane >> 2, seg = lane & 3;                  // 16 rows x 4 segs of 8
      const u16* src = Ep + rw * 40 + seg * 8;
      u16* gd = dstRow + (size_t)(row0 + wm + m * 16 + rw) * rowPitch + colBase + wn + seg * 8;
      *(uint4*)gd = *(const uint4*)src;                    // 4 lanes x 16B = 64B line
    } else {
      int c = lane >> 1, half = lane & 1;                  // 32 cols x 2 halves of 8 rows
      u16 tmp[8];
      #pragma unroll
      for (int j = 0; j < 8; ++j) tmp[j] = Ep[(half * 8 + j) * 40 + c];
      u16* gd = dstCol + (size_t)(colBase + wn + c) * 4096 + row0 + wm + m * 16 + half * 8;
      *(uint4*)gd = *(const uint4*)tmp;                    // 2 lanes x 16B = 32B per col
    }
  }
}

// ---------------- stage one 64x64 bf16 tile (512 threads, 1 uint4 each) -> LDS [64][72] ----------------
static __device__ __forceinline__ void stage_tile512(const u16* __restrict__ g, int gp, u16* L, int tid) {
  int row = tid >> 3, col8 = (tid & 7) << 3;
  *(uint4*)(L + row * 72 + col8) = *(const uint4*)(g + (size_t)row * gp + col8);
}

// ---------------- attention pass 1 (MFMA, 8 waves, 2 s-tiles/block) ----------------
// csum[s] = sum_t exp(S[t][s]); no-max softmax (S small, exp-safe; shift-invariant).
__global__ __launch_bounds__(512) void k_attn_stats_mfma(const u16* __restrict__ Qb, const u16* __restrict__ Kb,
                                                         float* __restrict__ csum) {
  __shared__ u16 Ks[2 * 4608];
  __shared__ u16 Qs[4608];
  int tid = threadIdx.x, wave = tid >> 6, lane = tid & 63;
  int tileIdx, bh;
  swz_attn(tileIdx, bh);
  int b = bh >> 4, h = bh & 15;
  int s0 = tileIdx << 7;                  // 128 s-cols per block
  int tile = wave >> 2, sw = wave & 3;
  stage_tile512(Kb + ((size_t)(b * TT + s0)) * DD + h * 64, DD, Ks, tid);
  stage_tile512(Kb + ((size_t)(b * TT + s0 + 64)) * DD + h * 64, DD, Ks + 4608, tid);
  int row = tid >> 3, col8 = (tid & 7) << 3;
  const u16* Qg = Qb + ((size_t)(b * TT) + row) * DD + h * 64 + col8;
  uint4 qreg = *(const uint4*)Qg;          // tile t0=0
  __syncthreads();                          // Ks visible
  int fr = lane & 15, g = lane >> 4;
  const u16* Bbase = Ks + tile * 4608 + (sw * 16 + fr) * 72 + g * 8;   // B-frag: K rows (n = s)
  const u16* Abase = Qs + fr * 72 + g * 8;                             // A-frag: Q rows (m = t)
  s16x8 bF0 = *(const s16x8*)(Bbase);
  s16x8 bF1 = *(const s16x8*)(Bbase + 32);
  float sum = 0.f;
  for (int t0 = 0; t0 < TT; t0 += 64) {
    __syncthreads();                        // prior Qs reads done
    *(uint4*)(Qs + row * 72 + col8) = qreg;
    __syncthreads();                        // Qs visible
    if (t0 + 64 < TT) qreg = *(const uint4*)(Qg + (size_t)(t0 + 64) * DD);
    #pragma unroll
    for (int mt = 0; mt < 4; ++mt) {
      f32x4 acc = f32x4{0.f, 0.f, 0.f, 0.f};
      s16x8 a0 = *(const s16x8*)(Abase + mt * 16 * 72);
      s16x8 a1 = *(const s16x8*)(Abase + mt * 16 * 72 + 32);
      acc = __builtin_amdgcn_mfma_f32_16x16x32_bf16(a0, bF0, acc, 0, 0, 0);
      acc = __builtin_amdgcn_mfma_f32_16x16x32_bf16(a1, bF1, acc, 0, 0, 0);
      sum += __expf(acc[0] * 0.125f) + __expf(acc[1] * 0.125f)
           + __expf(acc[2] * 0.125f) + __expf(acc[3] * 0.125f);
    }
  }
  sum += __shfl_xor(sum, 16, 64);
  sum += __shfl_xor(sum, 32, 64);
  if (lane < 16) csum[(size_t)bh * TT + s0 + tile * 64 + sw * 16 + lane] = sum;
}

// ---------------- attention pass 2 (MFMA, 8 waves, 2 t-tiles/block) ----------------
__global__ __launch_bounds__(512) void k_attn_apply_mfma(const u16* __restrict__ Qb, const u16* __restrict__ Kb,
                                                         const u16* __restrict__ Vt,
                                                         const float* __restrict__ csum,
                                                         u16* __restrict__ Op) {
  __shared__ u16 Qs[2 * 4608];
  __shared__ u16 KV2[2 * 4608];    // Ks | VTs; reused by the write epilogue
  __shared__ u16 Pl[8 * 1024];     // per-wave [16 t][64 s] bf16, XOR-swizzled
  __shared__ float rcsL[64];
  u16* Ks = KV2;
  u16* VTs = KV2 + 4608;
  int tid = threadIdx.x, wave = tid >> 6, lane = tid & 63;
  int tileIdx, bh;
  swz_attn(tileIdx, bh);
  int b = bh >> 4, h = bh & 15;
  int t0 = tileIdx << 7;                  // 128 t-rows per block
  int tile = wave >> 2, tw = wave & 3;
  stage_tile512(Qb + ((size_t)(b * TT + t0)) * DD + h * 64, DD, Qs, tid);
  stage_tile512(Qb + ((size_t)(b * TT + t0 + 64)) * DD + h * 64, DD, Qs + 4608, tid);
  int row = tid >> 3, col8 = (tid & 7) << 3;
  const u16* Kg = Kb + ((size_t)(b * TT) + row) * DD + h * 64 + col8;
  const u16* Vg = Vt + ((size_t)(h * 64) + row) * 4096 + (size_t)b * TT + col8;
  const size_t cbase = (size_t)bh * TT;
  uint4 kreg = *(const uint4*)Kg;          // s0 = 0
  uint4 vreg = *(const uint4*)Vg;
  float rc0 = (tid < 64) ? csum[cbase + tid] : 0.f;
  __syncthreads();                          // Qs visible
  int fr = lane & 15, g = lane >> 4;
  const u16* QbF = Qs + tile * 4608 + (tw * 16 + fr) * 72 + g * 8;   // B-frag (n = t)
  const u16* KaF = Ks + fr * 72 + g * 8;                             // A-frag rows s
  char* Pw = (char*)(Pl + wave * 1024);
  uint swz = ((uint)(lane & 7)) << 4;
  s16x8 qF0 = *(const s16x8*)(QbF);
  s16x8 qF1 = *(const s16x8*)(QbF + 32);
  f32x4 acc_o[4];
  #pragma unroll
  for (int nt = 0; nt < 4; ++nt) acc_o[nt] = f32x4{0.f, 0.f, 0.f, 0.f};

  for (int s0 = 0; s0 < TT; s0 += 64) {
    __syncthreads();                        // prior Ks/VTs reads done
    *(uint4*)(Ks + row * 72 + col8) = kreg;
    *(uint4*)(VTs + row * 72 + col8) = vreg;
    if (tid < 64) rcsL[tid] = 1.f / rc0;
    __syncthreads();                        // visible
    if (s0 + 64 < TT) {                     // issue next-tile loads; hide under compute
      kreg = *(const uint4*)(Kg + (size_t)(s0 + 64) * DD);
      vreg = *(const uint4*)(Vg + s0 + 64);
      if (tid < 64) rc0 = csum[cbase + s0 + 64 + tid];
    }
    // S^T tiles + exp -> P (per-wave)
    #pragma unroll
    for (int mt = 0; mt < 4; ++mt) {
      f32x4 acc = f32x4{0.f, 0.f, 0.f, 0.f};
      s16x8 a0 = *(const s16x8*)(KaF + mt * 16 * 72);
      s16x8 a1 = *(const s16x8*)(KaF + mt * 16 * 72 + 32);
      acc = __builtin_amdgcn_mfma_f32_16x16x32_bf16(a0, qF0, acc, 0, 0, 0);
      acc = __builtin_amdgcn_mfma_f32_16x16x32_bf16(a1, qF1, acc, 0, 0, 0);
      f32x4 rc4 = *(const f32x4*)&rcsL[mt * 16 + g * 4];
      u16 pb[4];
      #pragma unroll
      for (int r = 0; r < 4; ++r)
        pb[r] = f2bf(__expf(acc[r] * 0.125f) * rc4[r]);
      uint woff = (uint)fr * 128 + (uint)(mt * 16 + g * 4) * 2;
      uint2 wv; wv.x = (u32)pb[0] | ((u32)pb[1] << 16); wv.y = (u32)pb[2] | ((u32)pb[3] << 16);
      *(uint2*)(Pw + (woff ^ swz)) = wv;
    }
    // PV: A = P (own wave's tile), B = V^T
    uint rbase = (uint)fr * 128;
    s16x8 pF0 = *(const s16x8*)(Pw + ((rbase + g * 16) ^ swz));
    s16x8 pF1 = *(const s16x8*)(Pw + ((rbase + 64 + g * 16) ^ swz));
    #pragma unroll
    for (int nt = 0; nt < 4; ++nt) {
      s16x8 v0 = *(const s16x8*)(VTs + (nt * 16 + fr) * 72 + g * 8);
      s16x8 v1 = *(const s16x8*)(VTs + (nt * 16 + fr) * 72 + 32 + g * 8);
      acc_o[nt] = __builtin_amdgcn_mfma_f32_16x16x32_bf16(pF0, v0, acc_o[nt], 0, 0, 0);
      acc_o[nt] = __builtin_amdgcn_mfma_f32_16x16x32_bf16(pF1, v1, acc_o[nt], 0, 0, 0);
    }
  }
  // write epilogue: per-wave LDS transpose (reuse KV2) -> coalesced 32B/lane stores
  __syncthreads();                         // all waves done reading Ks/VTs
  u16* Ep = KV2 + wave * 1088;             // per-wave [16][68]
  #pragma unroll
  for (int nt = 0; nt < 4; ++nt)
    #pragma unroll
    for (int r = 0; r < 4; ++r)
      Ep[(g * 4 + r) * 68 + nt * 16 + fr] = f2bf(acc_o[nt][r]);
  {
    int rw = lane >> 2, seg = lane & 3;
    const u16* src = Ep + rw * 68 + seg * 16;
    u16* gd = Op + ((size_t)(b * TT + t0 + tile * 64 + tw * 16 + rw)) * DD + h * 64 + seg * 16;
    #pragma unroll
    for (int i = 0; i < 4; ++i) *(uint2*)(gd + i * 4) = *(const uint2*)(src + i * 4);
  }
}

// ---------------- O = norm(sum of bf16 partials + bias + residual), ddof=1 ----------------
__global__ __launch_bounds__(256) void k_add_norm(const u16* __restrict__ A, const u16* __restrict__ A2,
                                                  const u16* __restrict__ A3, const u16* __restrict__ A4,
                                                  const float* __restrict__ bias,
                                                  const float* __restrict__ Bv,
                                                  float* __restrict__ O, u16* __restrict__ Ob) {
  int row = blockIdx.x, tid = threadIdx.x;
  size_t base = (size_t)row * DD;
  int c0 = tid * 4;
  __shared__ float red[256];
  float v[4];
  {
    ushort4 a = *(const ushort4*)(A + base + c0);
    float4 bv = *(const float4*)(Bv + base + c0);
    v[0] = bf2f(a.x) + bv.x; v[1] = bf2f(a.y) + bv.y;
    v[2] = bf2f(a.z) + bv.z; v[3] = bf2f(a.w) + bv.w;
  }
  if (A2) {
    ushort4 a = *(const ushort4*)(A2 + base + c0);
    v[0] += bf2f(a.x); v[1] += bf2f(a.y); v[2] += bf2f(a.z); v[3] += bf2f(a.w);
  }
  if (A3) {
    ushort4 a = *(const ushort4*)(A3 + base + c0);
    v[0] += bf2f(a.x); v[1] += bf2f(a.y); v[2] += bf2f(a.z); v[3] += bf2f(a.w);
  }
  if (A4) {
    ushort4 a = *(const ushort4*)(A4 + base + c0);
    v[0] += bf2f(a.x); v[1] += bf2f(a.y); v[2] += bf2f(a.z); v[3] += bf2f(a.w);
  }
  if (bias) {
    float4 bs = *(const float4*)(bias + c0);
    v[0] += bs.x; v[1] += bs.y; v[2] += bs.z; v[3] += bs.w;
  }
  float s = v[0] + v[1] + v[2] + v[3];
  red[tid] = s; __syncthreads();
  for (int t = 128; t > 0; t >>= 1) { if (tid < t) red[tid] += red[tid + t]; __syncthreads(); }
  float mean = red[0] * (1.f / 1024.f);
  __syncthreads();
  float vs = 0.f;
  #pragma unroll
  for (int i = 0; i < 4; ++i) { float d = v[i] - mean; vs += d * d; }
  red[tid] = vs; __syncthreads();
  for (int t = 128; t > 0; t >>= 1) { if (tid < t) red[tid] += red[tid + t]; __syncthreads(); }
  float inv = rsqrtf(red[0] * (1.f / 1023.f));
  float o[4];
  #pragma unroll
  for (int i = 0; i < 4; ++i) o[i] = (v[i] - mean) * inv;
  *(float4*)(O + base + c0) = *(float4*)o;
  if (Ob) {
    u16 ob[4] = { f2bf(o[0]), f2bf(o[1]), f2bf(o[2]), f2bf(o[3]) };
    *(ushort4*)(Ob + base + c0) = *(ushort4*)ob;
  }
}

extern "C" void kernel_launch(void* const* d_in, const int* in_sizes, int n_in,
                              void* d_out, int out_size, void* d_ws, size_t ws_size,
                              hipStream_t stream) {
  (void)in_sizes; (void)n_in; (void)out_size; (void)ws_size;
  const float* x    = (const float*)d_in[0];
  const float* y    = (const float*)d_in[1];
  const float* Wq1  = (const float*)d_in[2];
  const float* Wk1  = (const float*)d_in[3];
  const float* Wv1  = (const float*)d_in[4];
  const float* Wo1  = (const float*)d_in[5];
  const float* Wq2  = (const float*)d_in[6];
  const float* Wk2  = (const float*)d_in[7];
  const float* Wv2  = (const float*)d_in[8];
  const float* Wo2  = (const float*)d_in[9];
  const float* w_in  = (const float*)d_in[10];
  const float* b_in  = (const float*)d_in[11];
  const float* w_out = (const float*)d_in[12];
  const float* b_out = (const float*)d_in[13];

  float* ws = (float*)d_ws;
  size_t off = 0;
  auto allocw = [&](size_t nw) { float* p = ws + off; off += nw; return p; };
  const size_t MR = (size_t)BB * TT;           // 4096
  const size_t ND = MR * DD;                   // 4.19M elems

  u16* Bq   = (u16*)allocw(512 * 1024);        // Bq|Bk|Bv contiguous => fused B (3072 x 1024)
  u16* Bk   = (u16*)allocw(512 * 1024);
  u16* Bv   = (u16*)allocw(512 * 1024);
  u16* Bwo1 = (u16*)allocw(512 * 1024);
  u16* B2   = (u16*)allocw(3 * 512 * 1024);    // [Bq2|Bk2|Bv2] contiguous (3072 x 1024)
  u16* Bwo2 = (u16*)allocw(512 * 1024);
  u16* Wi   = (u16*)allocw(2 * 1024 * 1024);
  u16* Wob  = (u16*)allocw(2 * 1024 * 1024);
  u16* xbf  = (u16*)allocw(ND / 2);
  u16* ybf  = (u16*)allocw(ND / 2);
  u16* REG  = (u16*)allocw(ND * 2);
  float* ff2  = allocw(ND);                    // partial slabs p0|p1 (bf16)
  float* out1 = allocw(ND);                    // residual; later partial slabs p2|p3
  float* out2 = allocw(ND);
  float* csum = allocw((size_t)BB * HH * TT);

  u16* Qb = REG;
  u16* Kb = REG + ND;
  u16* Vt = REG + 2 * ND;   // V col-major (1024 x 4096), pitch 4096
  u16* Mb = REG + 3 * ND;   // mhaO; also out1_bf between layers
  u16* ff1b = REG;
  u16* out2bf = ybf;
  float* doutHi = (float*)d_out + ND;
  u16* p0 = (u16*)ff2;          // bf16 partial slabs
  u16* p1 = (u16*)ff2 + ND;
  u16* p2 = (u16*)out1;         // only after out1 is dead (FF2)
  u16* p3 = (u16*)out1 + ND;

  dim3 blk(256), blkG(512), blkA(512);
  dim3 gPrep(18048);
  dim3 gQKV(24, 32);         // N=3072
  dim3 gP2(8, 32, 2);        // N=1024, split-K=2
  dim3 gF1(32, 32);          // N=4096
  dim3 gFF2(8, 32, 4);       // N=1024, split-K=4 (K=4096)
  dim3 gAttn(8, 64);         // (tiles, bh) + swz_attn -> per-XCD bh grouping
  dim3 gNorm(MR);

  // ONE launch: all conversions + all weight transforms (heavy segments first)
  k_prep_all<<<gPrep, blk, 0, stream>>>(x, (float*)d_out, xbf, y, ybf, w_in, Wi, w_out, Wob,
                                        Wq1, Wk1, Bq, Bk, Wv1, Bv,
                                        Wq2, Wk2, Wv2, B2, Wo1, Bwo1, Wo2, Bwo2);

  // ---- Layer 1: masked self-attention on y ----
  k_mfma_nt<<<gQKV, blkG, 0, stream>>>(ybf, nullptr, Bq, nullptr, nullptr, nullptr, nullptr, Qb, Kb, Vt, nullptr, 0, 1, 4096, 3072, 1024);
  k_attn_stats_mfma<<<gAttn, blkA, 0, stream>>>(Qb, Kb, csum);
  k_attn_apply_mfma<<<gAttn, blkA, 0, stream>>>(Qb, Kb, Vt, csum, Mb);
  // out-proj split-K=2: bf16 partials p0,p1
  k_mfma_nt<<<gP2, blkG, 0, stream>>>(Mb, nullptr, Bwo1, p0, p1, nullptr, nullptr, nullptr, nullptr, nullptr, nullptr, 0, 0, 4096, 1024, 1024);
  k_add_norm<<<gNorm, blk, 0, stream>>>(p0, p1, nullptr, nullptr, nullptr, y, out1, Mb /* out1_bf */);

  // ---- Layer 2: cross-attention (Q from out1, K/V from x) ----
  // fused QKV2: Q-cols read A=Mb (out1_bf), K/V-cols read A2=xbf; B=[Bq2|Bk2|Bv2]
  k_mfma_nt<<<gQKV, blkG, 0, stream>>>(Mb, xbf, B2, nullptr, nullptr, nullptr, nullptr, Qb, Kb, Vt, nullptr, 0, 1, 4096, 3072, 1024);
  k_attn_stats_mfma<<<gAttn, blkA, 0, stream>>>(Qb, Kb, csum);
  k_attn_apply_mfma<<<gAttn, blkA, 0, stream>>>(Qb, Kb, Vt, csum, Mb);
  // out-proj split-K=2: bf16 partials p0,p1
  k_mfma_nt<<<gP2, blkG, 0, stream>>>(Mb, nullptr, Bwo2, p0, p1, nullptr, nullptr, nullptr, nullptr, nullptr, nullptr, 0, 0, 4096, 1024, 1024);
  k_add_norm<<<gNorm, blk, 0, stream>>>(p0, p1, nullptr, nullptr, nullptr, out1, out2, out2bf);

  // ---- FF ----  (out1 dead from here; p2/p3 alias it)
  k_mfma_nt<<<gF1, blkG, 0, stream>>>(out2bf, nullptr, Wi, nullptr, nullptr, nullptr, nullptr, ff1b, nullptr, nullptr, b_in, 1, 0, 4096, 4096, 1024);
  // FF2 split-K=4: bf16 partials p0..p3; bias ONCE in final norm
  k_mfma_nt<<<gFF2, blkG, 0, stream>>>(ff1b, nullptr, Wob, p0, p1, p2, p3, nullptr, nullptr, nullptr, nullptr, 0, 0, 4096, 1024, 4096);
  k_add_norm<<<gNorm, blk, 0, stream>>>(p0, p1, p2, p3, b_out, out2, doutHi, nullptr);
}